// Round 1
// baseline (18786.493 us; speedup 1.0000x reference)
//
#include <hip/hip_runtime.h>
#include <cfloat>
#include <cmath>

// ---- problem constants ----
constexpr int kV   = 50257;
constexpr int kVP  = 50432;   // padded vocab stride for embT (= 197*256)
constexpr int kD   = 768;
constexpr int NLY  = 2;
constexpr int BB   = 4;
constexpr int BEAM = 5;
constexpr int RR   = BB * BEAM;   // 20 rows
constexpr int BUFL = 17;
constexpr int SS   = 128;
constexpr int DFF  = 3072;
constexpr int TMAX = 16;
constexpr int SOS  = 1;
constexpr int EOSt = 2;
constexpr int LB   = (kV + 255) / 256;  // 197 logits blocks
constexpr int NBLK = 256;               // persistent grid size (1 block/CU nominal)
constexpr size_t CSEG = (size_t)RR * BUFL * 768;
#define NEGV (-1e20f)

static_assert(RR * 768 == 15360, "A-tile size");

// ---------------- wave helpers ----------------
__device__ inline float wave_sum(float v) {
#pragma unroll
  for (int o = 32; o > 0; o >>= 1) v += __shfl_xor(v, o, 64);
  return v;
}
__device__ inline float wave_max(float v) {
#pragma unroll
  for (int o = 32; o > 0; o >>= 1) v = fmaxf(v, __shfl_xor(v, o, 64));
  return v;
}
__device__ inline bool better(float v1, int i1, float v2, int i2) {
  return v1 > v2 || (v1 == v2 && i1 < i2);
}
__device__ inline void insert5(float* tv, int* ti, float v, int i) {
  if (better(v, i, tv[4], ti[4])) {
    tv[4] = v; ti[4] = i;
#pragma unroll
    for (int s = 4; s > 0; --s)
      if (better(tv[s], ti[s], tv[s - 1], ti[s - 1])) {
        float fv = tv[s]; tv[s] = tv[s - 1]; tv[s - 1] = fv;
        int iv = ti[s]; ti[s] = ti[s - 1]; ti[s - 1] = iv;
      }
  }
}
__device__ inline float sel5f(const float* a, int i) {
  float r = a[0];
  r = (i == 1) ? a[1] : r; r = (i == 2) ? a[2] : r;
  r = (i == 3) ? a[3] : r; r = (i == 4) ? a[4] : r;
  return r;
}
__device__ inline int sel5i(const int* a, int i) {
  int r = a[0];
  r = (i == 1) ? a[1] : r; r = (i == 2) ? a[2] : r;
  r = (i == 3) ? a[3] : r; r = (i == 4) ? a[4] : r;
  return r;
}
__device__ inline void merge5(float* av, int* ai, const float* bv, const int* bi) {
  float cv[5]; int ci[5];
  int ia = 0, ib = 0;
#pragma unroll
  for (int s = 0; s < 5; ++s) {
    float va = sel5f(av, ia); int xa = sel5i(ai, ia);
    float vb = sel5f(bv, ib); int xb = sel5i(bi, ib);
    bool ta = better(va, xa, vb, xb);
    cv[s] = ta ? va : vb; ci[s] = ta ? xa : xb;
    ia += ta ? 1 : 0; ib += ta ? 0 : 1;
  }
#pragma unroll
  for (int s = 0; s < 5; ++s) { av[s] = cv[s]; ai[s] = ci[s]; }
}
__device__ inline float4 f4add(float4 a, float4 b) {
  return make_float4(a.x + b.x, a.y + b.y, a.z + b.z, a.w + b.w);
}

// ---------------- grid barrier (device-scope, sense via generation counter) ----------------
// bar[0]=count, bar[1]=generation. All NBLK blocks call this the same number of times.
__device__ __forceinline__ void grid_sync(int* bar) {
  __syncthreads();
  if (threadIdx.x == 0) {
    int* cnt = bar; int* gen = bar + 1;
    const int g = __hip_atomic_load(gen, __ATOMIC_RELAXED, __HIP_MEMORY_SCOPE_AGENT);
    const int prev = __hip_atomic_fetch_add(cnt, 1, __ATOMIC_ACQ_REL, __HIP_MEMORY_SCOPE_AGENT);
    if (prev == NBLK - 1) {
      __hip_atomic_store(cnt, 0, __ATOMIC_RELAXED, __HIP_MEMORY_SCOPE_AGENT);
      __hip_atomic_fetch_add(gen, 1, __ATOMIC_RELEASE, __HIP_MEMORY_SCOPE_AGENT);
    } else {
      while (__hip_atomic_load(gen, __ATOMIC_RELAXED, __HIP_MEMORY_SCOPE_AGENT) == g)
        __builtin_amdgcn_s_sleep(2);
      __builtin_amdgcn_fence(__ATOMIC_ACQUIRE, "agent");
    }
  }
  __syncthreads();
}

// ---------------- init ----------------
__global__ void init_k(int* buf0, float* scores, int* bar) {
  int tid = threadIdx.x;
  if (tid < 16) bar[tid] = 0;
  if (tid < RR * BUFL) buf0[tid] = 0;
  __syncthreads();
  if (tid < BB) buf0[tid * BEAM * BUFL] = SOS;
  if (tid < RR) scores[tid] = (tid % BEAM == 0) ? 0.f : NEGV;
}

// ---------------- transpose: dst[c*ds + r] = src[r*C + c] ----------------
__global__ void transpose_k(const float* __restrict__ src, float* __restrict__ dst,
                            int R, int C, int ds) {
  __shared__ float tile[32][33];
  const int c0 = blockIdx.x * 32, r0 = blockIdx.y * 32;
  const int lx = threadIdx.x & 31, ly = threadIdx.x >> 5;  // 32 x 8
#pragma unroll
  for (int j = 0; j < 4; ++j) {
    int r = r0 + ly + j * 8;
    if (r < R && c0 + lx < C) tile[ly + j * 8][lx] = src[(size_t)r * C + c0 + lx];
  }
  __syncthreads();
#pragma unroll
  for (int j = 0; j < 4; ++j) {
    int c = c0 + ly + j * 8;
    if (c < C && r0 + lx < R) dst[(size_t)c * ds + r0 + lx] = tile[lx][ly + j * 8];
  }
}

// ---------------- cross K/V precompute (once per call) ----------------
template<bool WT>
__global__ __launch_bounds__(256) void crosskv_k(
    const float* __restrict__ ctx, const float* __restrict__ Wm0,
    const float* __restrict__ bias0, float* __restrict__ ck, float* __restrict__ cv) {
  const int l = blockIdx.z;
  const float* Wm = Wm0 + (size_t)l * 2304 * 768;
  const float* bias = bias0 + l * 2304;
  __shared__ float a_s[16 * 768];
  __shared__ float ps[4 * 64 * 17];
  const int tid = threadIdx.x;
  const int row0 = blockIdx.y * 16;
  for (int i = tid * 4; i < 16 * 768; i += 1024) {
    int rr = i / 768, k = i - rr * 768;
    *(float4*)&a_s[i] = *(const float4*)&ctx[(size_t)(row0 + rr) * 768 + k];
  }
  __syncthreads();
  const int w = tid >> 6, lane = tid & 63;
  const int colg = 768 + blockIdx.x * 64 + lane;
  const int kb = w * 192;
  float acc[16];
#pragma unroll
  for (int r = 0; r < 16; ++r) acc[r] = 0.f;
  for (int k4 = 0; k4 < 48; ++k4) {
    const int k = kb + k4 * 4;
    float w0, w1, w2, w3;
    if (WT) {
      w0 = Wm[(size_t)(k + 0) * 2304 + colg]; w1 = Wm[(size_t)(k + 1) * 2304 + colg];
      w2 = Wm[(size_t)(k + 2) * 2304 + colg]; w3 = Wm[(size_t)(k + 3) * 2304 + colg];
    } else {
      float4 wv = *(const float4*)&Wm[(size_t)colg * 768 + k];
      w0 = wv.x; w1 = wv.y; w2 = wv.z; w3 = wv.w;
    }
#pragma unroll
    for (int r = 0; r < 16; ++r) {
      float4 a = *(const float4*)&a_s[r * 768 + k];
      acc[r] = fmaf(a.x, w0, fmaf(a.y, w1, fmaf(a.z, w2, fmaf(a.w, w3, acc[r]))));
    }
  }
#pragma unroll
  for (int r = 0; r < 16; ++r) ps[(w * 64 + lane) * 17 + r] = acc[r];
  __syncthreads();
  for (int o = tid; o < 1024; o += 256) {
    int rr = o >> 6, cl = o & 63;
    int cg = 768 + blockIdx.x * 64 + cl;
    float v = bias[cg];
#pragma unroll
    for (int ww = 0; ww < 4; ++ww) v += ps[(ww * 64 + cl) * 17 + rr];
    int gr = row0 + rr;
    int b = gr >> 7, s = gr & 127;
    int c = cg - 768, kv = c / 768, n = c - kv * 768;
    float* dst = kv ? cv : ck;
    dst[((size_t)(l * 4 + b) * 128 + s) * 768 + n] = v;
  }
}

// ================= persistent-decode stage functions =================

// fused skinny GEMM (M=20, K=768), 64 cols/block, 4-wave in-block K-split.
// pre: 0 = stage xsrc raw; 1 = embed+pos (then LN); 2 = xsrc + tmp_in (then LN);
//      3 = xsrc + bias2 + sum of 4 ff2 partials (then LN)
// outmode: 0 plain, 1 relu, 2 tanh, 3 qkv-route (qb / kcl / vcl @ pos t)
// NOTE: the partial-sum buffer ps aliases the A-tile UN (extra __syncthreads guards it).
template<bool WT>
__device__ void gemm_stage(int vb, float* UN,
    const float* __restrict__ Wm, int wstride, const float* __restrict__ bias, int N,
    int pre, const float* __restrict__ xsrc, const float* __restrict__ tmp_in,
    const float* __restrict__ lng, const float* __restrict__ lnb,
    float* __restrict__ xout, int outmode, float* __restrict__ out0,
    float* __restrict__ kcl, float* __restrict__ vcl, int t,
    const float* __restrict__ embp, const float* __restrict__ posw,
    const int* __restrict__ bufn,
    const float* __restrict__ pf, const float* __restrict__ bias2) {
  __shared__ float mS[RR], rS[RR];
  __shared__ int tokS[RR];
  const int tid = threadIdx.x;
  float* a_s = UN;
  if (pre == 1 && tid < RR) tokS[tid] = bufn[tid * BUFL + t];
  __syncthreads();
  // ---- stage A (20x768) into LDS ----
  for (int i = tid * 4; i < RR * 768; i += 1024) {
    const int r = i / 768, k = i - r * 768;
    float4 v;
    if (pre == 0) {
      v = *(const float4*)&xsrc[i];
    } else if (pre == 1) {
      const float4 e = *(const float4*)&embp[(size_t)tokS[r] * 768 + k];
      const float4 pz = *(const float4*)&posw[(size_t)t * 768 + k];
      v = f4add(e, pz);
    } else if (pre == 2) {
      v = f4add(*(const float4*)&xsrc[i], *(const float4*)&tmp_in[i]);
    } else {  // pre == 3: residual + ff2 bias + 4 split-K partials
      float4 v0 = f4add(*(const float4*)&xsrc[i], *(const float4*)&bias2[k]);
      v0 = f4add(v0, *(const float4*)&pf[i]);
      v0 = f4add(v0, *(const float4*)&pf[15360 + i]);
      v0 = f4add(v0, *(const float4*)&pf[30720 + i]);
      v = f4add(v0, *(const float4*)&pf[46080 + i]);
    }
    *(float4*)&a_s[i] = v;
  }
  __syncthreads();
  if (pre != 0) {
    // in-block LayerNorm (redundant across blocks; deterministic)
    const int wq = tid >> 6, ln = tid & 63;
    for (int r = wq * 5; r < wq * 5 + 5; ++r) {
      float s = 0.f, q = 0.f;
      for (int k = ln; k < 768; k += 64) { const float v = a_s[r * 768 + k]; s += v; q += v * v; }
      s = wave_sum(s); q = wave_sum(q);
      if (ln == 0) {
        const float m = s / 768.f;
        const float var = q / 768.f - m * m;
        mS[r] = m; rS[r] = 1.f / sqrtf(var + 1e-5f);
      }
    }
    __syncthreads();
    for (int i = tid * 4; i < RR * 768; i += 1024) {
      const int r = i / 768, k = i - r * 768;
      float4 v = *(const float4*)&a_s[i];
      const float4 g = *(const float4*)&lng[k];
      const float4 b = *(const float4*)&lnb[k];
      const float m = mS[r], rs = rS[r];
      v = make_float4((v.x - m) * rs * g.x + b.x, (v.y - m) * rs * g.y + b.y,
                      (v.z - m) * rs * g.z + b.z, (v.w - m) * rs * g.w + b.w);
      *(float4*)&a_s[i] = v;
    }
    __syncthreads();
    if (xout != nullptr && vb == 0) {
      for (int i = tid * 4; i < RR * 768; i += 1024)
        *(float4*)&xout[i] = *(const float4*)&a_s[i];
    }
  }
  // ---- compute: wave w owns K-chunk [w*192, w*192+192), lane owns column ----
  const int w = tid >> 6, lane = tid & 63;
  const int colg = vb * 64 + lane;
  const int kb = w * 192;
  float acc[RR];
#pragma unroll
  for (int r = 0; r < RR; ++r) acc[r] = 0.f;
  for (int k4 = 0; k4 < 48; ++k4) {
    const int k = kb + k4 * 4;
    float w0, w1, w2, w3;
    if (WT) {
      w0 = Wm[(size_t)(k + 0) * wstride + colg];
      w1 = Wm[(size_t)(k + 1) * wstride + colg];
      w2 = Wm[(size_t)(k + 2) * wstride + colg];
      w3 = Wm[(size_t)(k + 3) * wstride + colg];
    } else {
      const float4 wv = *(const float4*)&Wm[(size_t)colg * 768 + k];
      w0 = wv.x; w1 = wv.y; w2 = wv.z; w3 = wv.w;
    }
#pragma unroll
    for (int r = 0; r < RR; ++r) {
      const float4 a = *(const float4*)&a_s[r * 768 + k];
      acc[r] = fmaf(a.x, w0, fmaf(a.y, w1, fmaf(a.z, w2, fmaf(a.w, w3, acc[r]))));
    }
  }
  __syncthreads();              // all waves done reading a_s -> ps may alias it
  float* ps = UN;
#pragma unroll
  for (int r = 0; r < RR; ++r) ps[(w * 64 + lane) * 21 + r] = acc[r];
  __syncthreads();
  for (int o = tid; o < RR * 64; o += 256) {
    const int r = o >> 6, cl = o & 63;
    const int cg = vb * 64 + cl;
    float v = bias[cg];
#pragma unroll
    for (int ww = 0; ww < 4; ++ww) v += ps[(ww * 64 + cl) * 21 + r];
    if (outmode == 1) v = fmaxf(v, 0.f);
    else if (outmode == 2) v = tanhf(v);
    if (outmode == 3) {
      if (cg < 768) out0[r * 768 + cg] = v;
      else if (cg < 1536) kcl[(r * BUFL + t) * 768 + (cg - 768)] = v;
      else vcl[(r * BUFL + t) * 768 + (cg - 1536)] = v;
    } else {
      out0[(size_t)r * N + cg] = v;
    }
  }
}

// KV-cache beam reorder (positions 0..t-1, old -> new by prevK), float4-vectorized
__device__ void reorder_stage(int vb, int nb, int t,
    const float* __restrict__ kco, const float* __restrict__ vco,
    float* __restrict__ kcn, float* __restrict__ vcn, const int* __restrict__ prevK) {
  const int per = 192 * t;            // float4s per (row, half)
  const int tot = 2 * RR * per;
  for (int i = vb * 256 + (int)threadIdx.x; i < tot; i += nb * 256) {
    const int half = i / (RR * per);
    int rem = i - half * RR * per;
    const int r = rem / per;
    rem -= r * per;
    const int p2 = rem / 192;
    const int d4 = (rem - p2 * 192) * 4;
    const int src = (r / BEAM) * BEAM + prevK[r];
    if (half == 0)
      *(float4*)&kcn[(r * BUFL + p2) * 768 + d4] = *(const float4*)&kco[(src * BUFL + p2) * 768 + d4];
    else
      *(float4*)&vcn[(r * BUFL + p2) * 768 + d4] = *(const float4*)&vco[(src * BUFL + p2) * 768 + d4];
  }
}

// self-attention: one (r,h) pair per block; 4-wave K staging, wave0 compute
__device__ void self_attn_stage(int vb, float* UN, const float* __restrict__ qb,
    const float* __restrict__ kcn, const float* __restrict__ vcn,
    float* __restrict__ outb, int t) {
  __shared__ float qs[64];
  __shared__ float pp[16];
  const int tid = threadIdx.x, w = tid >> 6, lane = tid & 63;
  const int r = vb % RR, hh = vb / RR;
  float* ks = UN;
  if (w == 0) qs[lane] = qb[r * 768 + hh * 64 + lane];
  for (int p2 = w; p2 <= t; p2 += 4)
    ks[p2 * 65 + lane] = kcn[(r * BUFL + p2) * 768 + hh * 64 + lane];
  __syncthreads();
  if (w == 0) {
    float s = -1e30f;
    if (lane <= t) {
      float a = 0.f;
#pragma unroll
      for (int d = 0; d < 64; ++d) a = fmaf(qs[d], ks[lane * 65 + d], a);
      s = a * 0.125f;
    }
    const float m = wave_max(s);
    const float pex = expf(s - m);        // lanes > t underflow to exact 0
    const float sum = wave_sum(pex);
    if (lane <= t) pp[lane] = pex / sum;
  }
  __syncthreads();
  if (w == 0) {
    const float* vbp = vcn + r * BUFL * 768 + hh * 64 + lane;
    float o = 0.f;
    for (int k = 0; k <= t; ++k) o = fmaf(pp[k], vbp[k * 768], o);
    outb[r * 768 + hh * 64 + lane] = o;
  }
}

// cross-attention: one (r,h) pair per block; 4-wave K staging + 4-wave V split
__device__ void cross_attn_stage(int vb, float* UN, const float* __restrict__ qb,
    const float* __restrict__ ck, const float* __restrict__ cv,
    const int* __restrict__ smask, float* __restrict__ outb) {
  __shared__ float qs[64];
  __shared__ float pp[128];
  __shared__ float vpart[4 * 64];
  const int tid = threadIdx.x, w = tid >> 6, lane = tid & 63;
  const int r = vb % RR, hh = vb / RR, b = r / BEAM;
  float* ks = UN;
  if (w == 0) qs[lane] = qb[r * 768 + hh * 64 + lane];
  for (int p2 = w; p2 < 128; p2 += 4)
    ks[p2 * 65 + lane] = ck[((size_t)b * 128 + p2) * 768 + hh * 64 + lane];
  __syncthreads();
  if (w == 0) {
    float a0 = 0.f, a1 = 0.f;
#pragma unroll
    for (int d = 0; d < 64; ++d) {
      a0 = fmaf(qs[d], ks[lane * 65 + d], a0);
      a1 = fmaf(qs[d], ks[(lane + 64) * 65 + d], a1);
    }
    float s0 = a0 * 0.125f, s1 = a1 * 0.125f;
    if (smask[b * 128 + lane] == 0)      s0 = -1e9f;
    if (smask[b * 128 + lane + 64] == 0) s1 = -1e9f;
    const float m = wave_max(fmaxf(s0, s1));
    const float p0 = expf(s0 - m), p1 = expf(s1 - m);
    const float sum = wave_sum(p0 + p1);
    pp[lane] = p0 / sum; pp[lane + 64] = p1 / sum;
  }
  __syncthreads();
  {
    const float* vbp = cv + (size_t)b * 128 * 768 + hh * 64 + lane;
    float o0 = 0.f, o1 = 0.f, o2 = 0.f, o3 = 0.f;
    for (int k = w * 32; k < w * 32 + 32; k += 4) {
      o0 = fmaf(pp[k + 0], vbp[(k + 0) * 768], o0);
      o1 = fmaf(pp[k + 1], vbp[(k + 1) * 768], o1);
      o2 = fmaf(pp[k + 2], vbp[(k + 2) * 768], o2);
      o3 = fmaf(pp[k + 3], vbp[(k + 3) * 768], o3);
    }
    vpart[w * 64 + lane] = (o0 + o1) + (o2 + o3);
  }
  __syncthreads();
  if (w == 0)
    outb[r * 768 + hh * 64 + lane] =
        (vpart[lane] + vpart[64 + lane]) + (vpart[128 + lane] + vpart[192 + lane]);
}

// ff2 split-K partials: 192 blocks = 48 col-tiles(16) x 4 k-tiles(768).
// Partials summed (plus bias) by the consumer's pre==3 staging.
template<bool WT>
__device__ void ff2A_stage(int vb, float* UN, const float* __restrict__ Wm,
                           const float* __restrict__ A, float* __restrict__ pf) {
  float* ps = UN;
  const int tid = threadIdx.x, w = tid >> 6, lane = tid & 63;
  const int cl = lane & 15, ksub = lane >> 4;
  const int kt = vb / 48, ct = vb - kt * 48;
  const int colg = ct * 16 + cl;
  const int kb = kt * 768 + w * 192 + ksub * 48;
  float acc[RR];
#pragma unroll
  for (int r = 0; r < RR; ++r) acc[r] = 0.f;
  for (int k4 = 0; k4 < 12; ++k4) {
    const int k = kb + k4 * 4;
    float w0, w1, w2, w3;
    if (WT) {
      w0 = Wm[(size_t)(k + 0) * 768 + colg];
      w1 = Wm[(size_t)(k + 1) * 768 + colg];
      w2 = Wm[(size_t)(k + 2) * 768 + colg];
      w3 = Wm[(size_t)(k + 3) * 768 + colg];
    } else {
      const float4 wv = *(const float4*)&Wm[(size_t)colg * 3072 + k];
      w0 = wv.x; w1 = wv.y; w2 = wv.z; w3 = wv.w;
    }
#pragma unroll
    for (int r = 0; r < RR; ++r) {
      const float4 a = *(const float4*)&A[r * 3072 + k];
      acc[r] = fmaf(a.x, w0, fmaf(a.y, w1, fmaf(a.z, w2, fmaf(a.w, w3, acc[r]))));
    }
  }
  const int seg = w * 4 + ksub;           // 0..15, k-ordered within this k-tile
#pragma unroll
  for (int r = 0; r < RR; ++r) ps[(seg * 16 + cl) * 21 + r] = acc[r];
  __syncthreads();
  for (int o = tid; o < RR * 16; o += 256) {
    const int r = o >> 4, c2 = o & 15;
    float v = 0.f;
#pragma unroll
    for (int s2 = 0; s2 < 16; ++s2) v += ps[(s2 * 16 + c2) * 21 + r];
    pf[kt * 15360 + r * 768 + ct * 16 + c2] = v;
  }
}

// logits + per-block online-softmax partials + per-(block,row) top-5
template<bool ET>
__device__ void logits_stage(int blk, float* UN,
    const float* __restrict__ hbuf, const float* __restrict__ embM,
    float* __restrict__ candV, int* __restrict__ candI,
    float* __restrict__ mrow, float* __restrict__ srow) {
  __shared__ float vv[4 * 256];
  float* hs = UN;
  const int tid = threadIdx.x;
  for (int i = tid * 4; i < RR * 768; i += 1024)
    *(float4*)&hs[i] = *(const float4*)&hbuf[i];
  __syncthreads();
  const int col = blk * 256 + tid;
  const bool valid = col < kV;
  const int colc = valid ? col : (kV - 1);
  float acc[RR];
#pragma unroll
  for (int r = 0; r < RR; ++r) acc[r] = 0.f;
  for (int k = 0; k < 768; k += 4) {
    float w0, w1, w2, w3;
    if (ET) {
      w0 = embM[(size_t)(k + 0) * kVP + col];
      w1 = embM[(size_t)(k + 1) * kVP + col];
      w2 = embM[(size_t)(k + 2) * kVP + col];
      w3 = embM[(size_t)(k + 3) * kVP + col];
    } else {
      const float4 wv = *(const float4*)&embM[(size_t)colc * 768 + k];
      w0 = wv.x; w1 = wv.y; w2 = wv.z; w3 = wv.w;
    }
#pragma unroll
    for (int r = 0; r < RR; ++r) {
      const float4 a = *(const float4*)&hs[r * 768 + k];
      acc[r] = fmaf(a.x, w0, fmaf(a.y, w1, fmaf(a.z, w2, fmaf(a.w, w3, acc[r]))));
    }
  }
  const int w = tid >> 6, lane = tid & 63;
  for (int g = 0; g < 5; ++g) {      // rows 4g..4g+3; wave w handles row 4g+w
#pragma unroll
    for (int j = 0; j < 4; ++j) vv[j * 256 + tid] = valid ? acc[g * 4 + j] : -FLT_MAX;
    __syncthreads();
    const int r = g * 4 + w;
    float v[4]; int gc[4]; bool used[4];
#pragma unroll
    for (int j = 0; j < 4; ++j) {
      v[j] = vv[w * 256 + lane * 4 + j];
      gc[j] = blk * 256 + lane * 4 + j;
      used[j] = false;
    }
    float tv[5]; int tg[5];
#pragma unroll
    for (int round = 0; round < 5; ++round) {
      float bv = -FLT_MAX; int bidx = 0x7fffffff; int bj = -1;
#pragma unroll
      for (int j = 0; j < 4; ++j) {
        const bool c = (!used[j]) && better(v[j], gc[j], bv, bidx);
        bv = c ? v[j] : bv; bidx = c ? gc[j] : bidx; bj = c ? j : bj;
      }
      float wv2 = bv; int wi = bidx;
      for (int d = 1; d < 64; d <<= 1) {
        const float ov = __shfl_xor(wv2, d, 64); const int oi = __shfl_xor(wi, d, 64);
        if (better(ov, oi, wv2, wi)) { wv2 = ov; wi = oi; }
      }
      tv[round] = wv2; tg[round] = wi;
      if (bj >= 0 && bidx == wi) used[bj] = true;
    }
    const float m = tv[0];
    float s = 0.f;
#pragma unroll
    for (int j = 0; j < 4; ++j) s += expf(v[j] - m);   // -FLT_MAX -> 0
    s = wave_sum(s);
    if (lane == 0) {
      mrow[r * LB + blk] = m;
      srow[r * LB + blk] = s;
#pragma unroll
      for (int q = 0; q < 5; ++q) {
        candV[(r * LB + blk) * 5 + q] = tv[q];
        candI[(r * LB + blk) * 5 + q] = tg[q];
      }
    }
    __syncthreads();
  }
}

// per-batch top-5 over candidates + lse-reduce + buf reorder
__device__ void topk_stage(int b, const float* __restrict__ candV, const int* __restrict__ candI,
    const float* __restrict__ mrow, const float* __restrict__ srow,
    float* __restrict__ scores, const int* __restrict__ bufc, int* __restrict__ bufn,
    int t, int* __restrict__ prevK, int* __restrict__ tokv) {
  const int tid = threadIdx.x;
  const int w = tid >> 6, lane = tid & 63;
  __shared__ float lseS[5], scS[5];
  __shared__ int emS[5];
  __shared__ float wv5[4][5]; __shared__ int wi5[4][5];
  __shared__ int fpk[5], ftok[5];
  for (int j = w; j < 5; j += 4) {
    const int gr = b * 5 + j;
    float M = -FLT_MAX, S = 0.f;
    for (int e = lane; e < LB; e += 64) {
      const float m2 = mrow[gr * LB + e], s2 = srow[gr * LB + e];
      if (m2 > M) { S = S * expf(M - m2) + s2; M = m2; }
      else        { S += s2 * expf(m2 - M); }
    }
    for (int d = 1; d < 64; d <<= 1) {
      const float Mo = __shfl_xor(M, d, 64), So = __shfl_xor(S, d, 64);
      const float Mn = fmaxf(M, Mo);
      S = S * expf(M - Mn) + So * expf(Mo - Mn);
      M = Mn;
    }
    if (lane == 0) {
      lseS[j] = M + logf(S);
      scS[j] = scores[gr];
      emS[j] = (bufc[gr * BUFL + t] == EOSt);
    }
  }
  __syncthreads();
  float tv[5]; int ti[5];
#pragma unroll
  for (int s = 0; s < 5; ++s) { tv[s] = -FLT_MAX; ti[s] = 0x7fffffff; }
  for (int i = tid; i < 5 * LB * 5; i += 256) {
    const int j = i / (LB * 5);
    const int e = i - j * (LB * 5);
    const int blk = e / 5, rk = e - blk * 5;
    const int gr = b * 5 + j;
    const float cvv = candV[(gr * LB + blk) * 5 + rk];
    const int col = candI[(gr * LB + blk) * 5 + rk];
    const float val = emS[j] ? NEGV : (cvv - lseS[j] + scS[j]);
    insert5(tv, ti, val, j * kV + col);
  }
  for (int d = 1; d < 64; d <<= 1) {
    float ov[5]; int oi[5];
#pragma unroll
    for (int s = 0; s < 5; ++s) { ov[s] = __shfl_xor(tv[s], d, 64); oi[s] = __shfl_xor(ti[s], d, 64); }
    merge5(tv, ti, ov, oi);
  }
  if (lane == 0) {
#pragma unroll
    for (int s = 0; s < 5; ++s) { wv5[w][s] = tv[s]; wi5[w][s] = ti[s]; }
  }
  __syncthreads();
  if (tid == 0) {
    float av[5]; int ai[5];
#pragma unroll
    for (int s = 0; s < 5; ++s) { av[s] = wv5[0][s]; ai[s] = wi5[0][s]; }
    for (int ww = 1; ww < 4; ++ww) {
      float bv[5]; int bi[5];
#pragma unroll
      for (int s = 0; s < 5; ++s) { bv[s] = wv5[ww][s]; bi[s] = wi5[ww][s]; }
      merge5(av, ai, bv, bi);
    }
#pragma unroll
    for (int s = 0; s < 5; ++s) {
      const int pk = ai[s] / kV;
      const int tk = ai[s] - pk * kV;
      scores[b * 5 + s] = av[s];
      prevK[b * 5 + s] = pk; tokv[b * 5 + s] = tk;
      fpk[s] = pk; ftok[s] = tk;
    }
  }
  __syncthreads();
  for (int i = tid; i < 5 * BUFL; i += 256) {
    const int j = i / BUFL, p2 = i - j * BUFL;
    const int src = b * 5 + fpk[j];
    const int val = (p2 == t + 1) ? ftok[j] : bufc[src * BUFL + p2];
    bufn[(b * 5 + j) * BUFL + p2] = val;
  }
}

// ================= the persistent decode kernel =================
struct DecP {
  const float *emb, *pos, *ln_emb_g, *ln_emb_b;
  const float *self_in_b, *self_out_b, *cross_in_b, *cross_out_b;
  const float *ff1_b, *ff2_b, *dense_b;
  const float *ln1_g, *ln1_b, *ln2_g, *ln2_b, *ln3_g, *ln3_b;
  const int* smask;
  const float *Wqkv0, *Wqkv1, *Wso0, *Wso1, *Wcq0, *Wcq1, *Wco0, *Wco1;
  const float *Wf10, *Wf11, *Wf20, *Wf21, *Wd, *embM;
  float *XA, *XB, *XC, *qb, *attnb, *tmp, *hbuf, *ffb, *pf;
  float *candV, *mrow, *srow, *scores;
  float *ck, *cv, *kcB, *vcB;
  int *candI, *bufs0, *bufs1, *prevK, *tok;
  int* bar;
  float* out;
};

template<bool WT, bool ET>
__global__ __launch_bounds__(256) void decode_k(DecP p) {
  __shared__ float UN[15360];   // A-tile / K-stage / partial-sum union (61.4 KB)
  const int vb = blockIdx.x;
#pragma unroll 1
  for (int t = 0; t < TMAX; ++t) {
    const int* bc = (t & 1) ? p.bufs1 : p.bufs0;
    int* bn = (t & 1) ? p.bufs0 : p.bufs1;
    const int np = (t + 1) & 1, op = t & 1;
#pragma unroll 1
    for (int l = 0; l < 2; ++l) {
      float* kNew = p.kcB + (size_t)(np * 2 + l) * CSEG;
      float* vNew = p.vcB + (size_t)(np * 2 + l) * CSEG;
      const float* kOld = p.kcB + (size_t)(op * 2 + l) * CSEG;
      const float* vOld = p.vcB + (size_t)(op * 2 + l) * CSEG;
      // ---- qkv (36 blocks) + cache reorder (remaining blocks) ----
      if (vb < 36) {
        if (l == 0)
          gemm_stage<WT>(vb, UN, p.Wqkv0, 2304, p.self_in_b, 2304,
                         1, nullptr, nullptr, p.ln_emb_g, p.ln_emb_b, p.XA,
                         3, p.qb, kNew, vNew, t, p.emb, p.pos, bc, nullptr, nullptr);
        else
          gemm_stage<WT>(vb, UN, p.Wqkv1, 2304, p.self_in_b + 2304, 2304,
                         3, p.XC, nullptr, p.ln3_g, p.ln3_b, p.XA,
                         3, p.qb, kNew, vNew, t, nullptr, nullptr, nullptr,
                         p.pf, p.ff2_b);
      } else if (t > 0) {
        reorder_stage(vb - 36, NBLK - 36, t, kOld, vOld, kNew, vNew, p.prevK);
      }
      grid_sync(p.bar);
      // ---- self attention (240 blocks, one (r,h) each) ----
      if (vb < RR * 12) self_attn_stage(vb, UN, p.qb, kNew, vNew, p.attnb, t);
      grid_sync(p.bar);
      // ---- self out-proj -> tmp ----
      if (vb < 12)
        gemm_stage<WT>(vb, UN, l ? p.Wso1 : p.Wso0, 768, p.self_out_b + l * 768, 768,
                       0, p.attnb, nullptr, nullptr, nullptr, nullptr,
                       0, p.tmp, nullptr, nullptr, t,
                       nullptr, nullptr, nullptr, nullptr, nullptr);
      grid_sync(p.bar);
      // ---- cross q (+ln1), writes XB ----
      if (vb < 12)
        gemm_stage<WT>(vb, UN, l ? p.Wcq1 : p.Wcq0, 2304, p.cross_in_b + l * 2304, 768,
                       2, p.XA, p.tmp, p.ln1_g + l * 768, p.ln1_b + l * 768, p.XB,
                       0, p.qb, nullptr, nullptr, t,
                       nullptr, nullptr, nullptr, nullptr, nullptr);
      grid_sync(p.bar);
      // ---- cross attention ----
      if (vb < RR * 12)
        cross_attn_stage(vb, UN, p.qb,
                         p.ck + (size_t)l * 4 * 128 * 768,
                         p.cv + (size_t)l * 4 * 128 * 768, p.smask, p.attnb);
      grid_sync(p.bar);
      // ---- cross out-proj -> tmp ----
      if (vb < 12)
        gemm_stage<WT>(vb, UN, l ? p.Wco1 : p.Wco0, 768, p.cross_out_b + l * 768, 768,
                       0, p.attnb, nullptr, nullptr, nullptr, nullptr,
                       0, p.tmp, nullptr, nullptr, t,
                       nullptr, nullptr, nullptr, nullptr, nullptr);
      grid_sync(p.bar);
      // ---- ff1 (+ln2), writes XC ----
      if (vb < 48)
        gemm_stage<WT>(vb, UN, l ? p.Wf11 : p.Wf10, 3072, p.ff1_b + l * 3072, 3072,
                       2, p.XB, p.tmp, p.ln2_g + l * 768, p.ln2_b + l * 768, p.XC,
                       1, p.ffb, nullptr, nullptr, t,
                       nullptr, nullptr, nullptr, nullptr, nullptr);
      grid_sync(p.bar);
      // ---- ff2 split-K partials (bias + reduce folded into consumer pre==3) ----
      if (vb < 192) ff2A_stage<WT>(vb, UN, l ? p.Wf21 : p.Wf20, p.ffb, p.pf);
      grid_sync(p.bar);
    }
    // ---- dense head (+ln3 layer1, tanh) -> hbuf ----
    if (vb < 12)
      gemm_stage<WT>(vb, UN, p.Wd, 768, p.dense_b, 768,
                     3, p.XC, nullptr, p.ln3_g + 768, p.ln3_b + 768, nullptr,
                     2, p.hbuf, nullptr, nullptr, t,
                     nullptr, nullptr, nullptr, p.pf, p.ff2_b + 768);
    grid_sync(p.bar);
    // ---- logits partials ----
    if (vb < LB) logits_stage<ET>(vb, UN, p.hbuf, p.embM, p.candV, p.candI, p.mrow, p.srow);
    grid_sync(p.bar);
    // ---- top-k + buf reorder ----
    if (vb < BB) topk_stage(vb, p.candV, p.candI, p.mrow, p.srow, p.scores, bc, bn, t, p.prevK, p.tok);
    grid_sync(p.bar);
  }
  // ---- finalize (buf parity: t=15 wrote bufs0) ----
  if (vb == 0) {
    const int tid = threadIdx.x;
    if (tid < RR) {
      p.out[tid] = p.scores[tid];
      int seen = 0;
      for (int i = 0; i < TMAX; ++i) {
        const int tk = p.bufs0[tid * BUFL + 1 + i];
        if (tk == EOSt) seen = 1;
        p.out[RR + tid * TMAX + i] = seen ? 0.f : (float)tk;
      }
    }
  }
}

// ================= host side =================
extern "C" void kernel_launch(void* const* d_in, const int* in_sizes, int n_in,
                              void* d_out, int out_size, void* d_ws, size_t ws_size,
                              hipStream_t stream) {
  const float* emb        = (const float*)d_in[0];
  const float* pos        = (const float*)d_in[1];
  const float* ln_emb_g   = (const float*)d_in[2];
  const float* ln_emb_b   = (const float*)d_in[3];
  const float* self_in_w  = (const float*)d_in[4];
  const float* self_in_b  = (const float*)d_in[5];
  const float* self_out_w = (const float*)d_in[6];
  const float* self_out_b = (const float*)d_in[7];
  const float* cross_in_w = (const float*)d_in[8];
  const float* cross_in_b = (const float*)d_in[9];
  const float* cross_out_w= (const float*)d_in[10];
  const float* cross_out_b= (const float*)d_in[11];
  const float* ff1_w      = (const float*)d_in[12];
  const float* ff1_b      = (const float*)d_in[13];
  const float* ff2_w      = (const float*)d_in[14];
  const float* ff2_b      = (const float*)d_in[15];
  const float* ln1_g      = (const float*)d_in[16];
  const float* ln1_b      = (const float*)d_in[17];
  const float* ln2_g      = (const float*)d_in[18];
  const float* ln2_b      = (const float*)d_in[19];
  const float* ln3_g      = (const float*)d_in[20];
  const float* ln3_b      = (const float*)d_in[21];
  const float* dense_w    = (const float*)d_in[22];
  const float* dense_b    = (const float*)d_in[23];
  const float* context    = (const float*)d_in[24];
  const int*   source_mask= (const int*)d_in[25];

  float* wsf = (float*)d_ws;
  size_t off = 0;
  auto alloc = [&](size_t n) { float* p = wsf + off; off += (n + 3) & ~(size_t)3; return p; };

  float* XA    = alloc(RR * 768);
  float* XB    = alloc(RR * 768);
  float* XC    = alloc(RR * 768);
  float* qb    = alloc(RR * 768);
  float* attnb = alloc(RR * 768);
  float* tmp   = alloc(RR * 768);
  float* hbuf  = alloc(RR * 768);
  float* ffb   = alloc(RR * 3072);
  float* candV = alloc(RR * LB * 5);
  float* mrow  = alloc(RR * LB);
  float* srow  = alloc(RR * LB);
  float* scores= alloc(32);
  float* ck    = alloc((size_t)NLY * 4 * 128 * 768);
  float* cv    = alloc((size_t)NLY * 4 * 128 * 768);
  float* kcB   = alloc(4 * CSEG);                 // [pp][l]
  float* vcB   = alloc(4 * CSEG);
  float* pf    = alloc(4 * RR * 768);             // ff2 split-K partials
  int* candI   = (int*)alloc(RR * LB * 5);
  int* bufs0   = (int*)alloc(RR * BUFL + 12);
  int* bufs1   = (int*)alloc(RR * BUFL + 12);
  int* prevKp  = (int*)alloc(32);
  int* tokp    = (int*)alloc(32);
  int* bar     = (int*)alloc(16);
  const size_t baseFloats = off;

  // transposed weights
  const size_t nSiT = (size_t)768 * 2304, nSoT = (size_t)768 * 768;
  const size_t nCiT = nSiT, nCoT = nSoT, nF1T = (size_t)768 * 3072, nF2T = (size_t)3072 * 768;
  const size_t wtFloats = 2 * (nSiT + nSoT + nCiT + nCoT + nF1T + nF2T) + nSoT;
  const size_t embTFloats = (size_t)768 * kVP;
  const bool useWT = ws_size >= (baseFloats + wtFloats) * 4;
  const bool useET = useWT && ws_size >= (baseFloats + wtFloats + embTFloats) * 4;

  float* siT[2]; float* soT[2]; float* ciT[2]; float* coT[2]; float* f1T[2]; float* f2T[2];
  float* dT = nullptr; float* embT = nullptr;
  if (useWT) {
    for (int l = 0; l < 2; ++l) siT[l] = alloc(nSiT);
    for (int l = 0; l < 2; ++l) soT[l] = alloc(nSoT);
    for (int l = 0; l < 2; ++l) ciT[l] = alloc(nCiT);
    for (int l = 0; l < 2; ++l) coT[l] = alloc(nCoT);
    for (int l = 0; l < 2; ++l) f1T[l] = alloc(nF1T);
    for (int l = 0; l < 2; ++l) f2T[l] = alloc(nF2T);
    dT = alloc(nSoT);
    if (useET) embT = alloc(embTFloats);
  }

  init_k<<<1, 512, 0, stream>>>(bufs0, scores, bar);

  if (useWT) {
    auto T = [&](const float* src, float* dst, int R, int C, int ds) {
      dim3 g((C + 31) / 32, (R + 31) / 32);
      transpose_k<<<g, 256, 0, stream>>>(src, dst, R, C, ds);
    };
    for (int l = 0; l < 2; ++l) {
      T(self_in_w  + (size_t)l * 2304 * 768, siT[l], 2304, 768, 2304);
      T(self_out_w + (size_t)l * 768 * 768,  soT[l], 768, 768, 768);
      T(cross_in_w + (size_t)l * 2304 * 768, ciT[l], 2304, 768, 2304);
      T(cross_out_w+ (size_t)l * 768 * 768,  coT[l], 768, 768, 768);
      T(ff1_w      + (size_t)l * 3072 * 768, f1T[l], 3072, 768, 3072);
      T(ff2_w      + (size_t)l * 768 * 3072, f2T[l], 768, 3072, 768);
    }
    T(dense_w, dT, 768, 768, 768);
    if (useET) T(emb, embT, kV, 768, kVP);
  }

  // cross K/V (once)
  {
    dim3 g(24, 32, 2);
    if (useWT) crosskv_k<true><<<g, 256, 0, stream>>>(context, ciT[0], cross_in_b, ck, cv);
    else       crosskv_k<false><<<g, 256, 0, stream>>>(context, cross_in_w, cross_in_b, ck, cv);
  }

  DecP P;
  P.emb = emb; P.pos = pos; P.ln_emb_g = ln_emb_g; P.ln_emb_b = ln_emb_b;
  P.self_in_b = self_in_b; P.self_out_b = self_out_b;
  P.cross_in_b = cross_in_b; P.cross_out_b = cross_out_b;
  P.ff1_b = ff1_b; P.ff2_b = ff2_b; P.dense_b = dense_b;
  P.ln1_g = ln1_g; P.ln1_b = ln1_b; P.ln2_g = ln2_g; P.ln2_b = ln2_b;
  P.ln3_g = ln3_g; P.ln3_b = ln3_b;
  P.smask = source_mask;
  if (useWT) {
    P.Wqkv0 = siT[0]; P.Wqkv1 = siT[1]; P.Wso0 = soT[0]; P.Wso1 = soT[1];
    P.Wcq0 = ciT[0]; P.Wcq1 = ciT[1]; P.Wco0 = coT[0]; P.Wco1 = coT[1];
    P.Wf10 = f1T[0]; P.Wf11 = f1T[1]; P.Wf20 = f2T[0]; P.Wf21 = f2T[1];
    P.Wd = dT; P.embM = useET ? embT : emb;
  } else {
    P.Wqkv0 = self_in_w; P.Wqkv1 = self_in_w + (size_t)2304 * 768;
    P.Wso0 = self_out_w; P.Wso1 = self_out_w + (size_t)768 * 768;
    P.Wcq0 = cross_in_w; P.Wcq1 = cross_in_w + (size_t)2304 * 768;
    P.Wco0 = cross_out_w; P.Wco1 = cross_out_w + (size_t)768 * 768;
    P.Wf10 = ff1_w; P.Wf11 = ff1_w + (size_t)3072 * 768;
    P.Wf20 = ff2_w; P.Wf21 = ff2_w + (size_t)768 * 3072;
    P.Wd = dense_w; P.embM = emb;
  }
  P.XA = XA; P.XB = XB; P.XC = XC; P.qb = qb; P.attnb = attnb; P.tmp = tmp;
  P.hbuf = hbuf; P.ffb = ffb; P.pf = pf;
  P.candV = candV; P.mrow = mrow; P.srow = srow; P.scores = scores;
  P.ck = ck; P.cv = cv; P.kcB = kcB; P.vcB = vcB;
  P.candI = candI; P.bufs0 = bufs0; P.bufs1 = bufs1; P.prevK = prevKp; P.tok = tokp;
  P.bar = bar; P.out = (float*)d_out;

  if (useET)      decode_k<true,  true ><<<NBLK, 256, 0, stream>>>(P);
  else if (useWT) decode_k<true,  false><<<NBLK, 256, 0, stream>>>(P);
  else            decode_k<false, false><<<NBLK, 256, 0, stream>>>(P);
}

// Round 8
// 16336.159 us; speedup vs baseline: 1.1500x; 1.1500x over previous
//
#include <hip/hip_runtime.h>
#include <cfloat>
#include <cmath>

// ---- problem constants ----
constexpr int kV   = 50257;
constexpr int kVP  = 50432;   // padded vocab stride for embT (= 197*256)
constexpr int kD   = 768;
constexpr int NLY  = 2;
constexpr int BB   = 4;
constexpr int BEAM = 5;
constexpr int RR   = BB * BEAM;   // 20 rows
constexpr int BUFL = 17;
constexpr int SS   = 128;
constexpr int DFF  = 3072;
constexpr int TMAX = 16;
constexpr int SOS  = 1;
constexpr int EOSt = 2;
constexpr int LB   = (kV + 255) / 256;  // 197 logits blocks
constexpr int NBLK = 256;               // persistent grid size (1 block/CU nominal)
constexpr size_t CSEG = (size_t)RR * BUFL * 768;
#define NEGV (-1e20f)

static_assert(RR * 768 == 15360, "A-tile size");
static_assert(NBLK == 256, "barrier tree assumes 256 blocks (8 groups of 32)");

// ---------------- coherent (agent-scope, L2-bypassing) access helpers ----------------
// All RW activation buffers are accessed ONLY through these, so grid barriers need no
// L2 writeback/invalidate: visibility is via sc stores (acked at coherence point before
// __syncthreads' vmcnt drain) + relaxed atomic counters.
// NOTE: call sites are arranged so consecutive LANES touch consecutive dwords
// (stride-1) -> each sc load/store instruction is a fully-coalesced 256B segment.
__device__ __forceinline__ float ldc(const float* p) {
  return __hip_atomic_load(p, __ATOMIC_RELAXED, __HIP_MEMORY_SCOPE_AGENT);
}
__device__ __forceinline__ void stc(float* p, float v) {
  __hip_atomic_store(p, v, __ATOMIC_RELAXED, __HIP_MEMORY_SCOPE_AGENT);
}
__device__ __forceinline__ int ldci(const int* p) {
  return __hip_atomic_load(p, __ATOMIC_RELAXED, __HIP_MEMORY_SCOPE_AGENT);
}
__device__ __forceinline__ void stci(int* p, int v) {
  __hip_atomic_store(p, v, __ATOMIC_RELAXED, __HIP_MEMORY_SCOPE_AGENT);
}

// ---------------- wave helpers ----------------
__device__ inline float wave_sum(float v) {
#pragma unroll
  for (int o = 32; o > 0; o >>= 1) v += __shfl_xor(v, o, 64);
  return v;
}
__device__ inline float wave_max(float v) {
#pragma unroll
  for (int o = 32; o > 0; o >>= 1) v = fmaxf(v, __shfl_xor(v, o, 64));
  return v;
}
__device__ inline bool better(float v1, int i1, float v2, int i2) {
  return v1 > v2 || (v1 == v2 && i1 < i2);
}
__device__ inline void insert5(float* tv, int* ti, float v, int i) {
  if (better(v, i, tv[4], ti[4])) {
    tv[4] = v; ti[4] = i;
#pragma unroll
    for (int s = 4; s > 0; --s)
      if (better(tv[s], ti[s], tv[s - 1], ti[s - 1])) {
        float fv = tv[s]; tv[s] = tv[s - 1]; tv[s - 1] = fv;
        int iv = ti[s]; ti[s] = ti[s - 1]; ti[s - 1] = iv;
      }
  }
}
__device__ inline float sel5f(const float* a, int i) {
  float r = a[0];
  r = (i == 1) ? a[1] : r; r = (i == 2) ? a[2] : r;
  r = (i == 3) ? a[3] : r; r = (i == 4) ? a[4] : r;
  return r;
}
__device__ inline int sel5i(const int* a, int i) {
  int r = a[0];
  r = (i == 1) ? a[1] : r; r = (i == 2) ? a[2] : r;
  r = (i == 3) ? a[3] : r; r = (i == 4) ? a[4] : r;
  return r;
}
__device__ inline void merge5(float* av, int* ai, const float* bv, const int* bi) {
  float cv[5]; int ci[5];
  int ia = 0, ib = 0;
#pragma unroll
  for (int s = 0; s < 5; ++s) {
    float va = sel5f(av, ia); int xa = sel5i(ai, ia);
    float vb = sel5f(bv, ib); int xb = sel5i(bi, ib);
    bool ta = better(va, xa, vb, xb);
    cv[s] = ta ? va : vb; ci[s] = ta ? xa : xb;
    ia += ta ? 1 : 0; ib += ta ? 0 : 1;
  }
#pragma unroll
  for (int s = 0; s < 5; ++s) { av[s] = cv[s]; ai[s] = ci[s]; }
}
__device__ inline float4 f4add(float4 a, float4 b) {
  return make_float4(a.x + b.x, a.y + b.y, a.z + b.z, a.w + b.w);
}

// ---------------- grid barrier ----------------
// Monotonic counters (no reset -> no reuse hazard), padded to separate 256B lines:
//   bar[0]            : master counter (8 increments per barrier)
//   bar[64]           : generation (polled; read-only for pollers -> no line ping-pong)
//   bar[128 + 64*g]   : sub-counter for group g = blockIdx.x & 7 (32 increments each)
// Data coherence comes from sc loads/stores, NOT from this barrier (no wbl2/inv).
__device__ __forceinline__ void grid_sync(int* bar, int bs) {
  __syncthreads();   // compiler drains vmcnt(0) per wave before s_barrier -> sc stores visible
  if (threadIdx.x == 0) {
    asm volatile("s_waitcnt vmcnt(0)" ::: "memory");  // insurance
    int* gen = bar + 64;
    int* sub = bar + 128 + (blockIdx.x & 7) * 64;
    if (__hip_atomic_fetch_add(sub, 1, __ATOMIC_RELAXED, __HIP_MEMORY_SCOPE_AGENT) == 32 * bs - 1) {
      if (__hip_atomic_fetch_add(bar, 1, __ATOMIC_RELAXED, __HIP_MEMORY_SCOPE_AGENT) == 8 * bs - 1) {
        __hip_atomic_store(gen, bs, __ATOMIC_RELAXED, __HIP_MEMORY_SCOPE_AGENT);
      }
    }
    while (__hip_atomic_load(gen, __ATOMIC_RELAXED, __HIP_MEMORY_SCOPE_AGENT) < bs)
      __builtin_amdgcn_s_sleep(4);
  }
  asm volatile("" ::: "memory");
  __syncthreads();
}

// ---------------- init ----------------
__global__ void init_k(int* buf0, float* scores, int* bar) {
  int tid = threadIdx.x;
  for (int i = tid; i < 1024; i += 512) bar[i] = 0;
  if (tid < RR * BUFL) buf0[tid] = 0;
  __syncthreads();
  if (tid < BB) buf0[tid * BEAM * BUFL] = SOS;
  if (tid < RR) scores[tid] = (tid % BEAM == 0) ? 0.f : NEGV;
}

// ---------------- transpose: dst[c*ds + r] = src[r*C + c] ----------------
__global__ void transpose_k(const float* __restrict__ src, float* __restrict__ dst,
                            int R, int C, int ds) {
  __shared__ float tile[32][33];
  const int c0 = blockIdx.x * 32, r0 = blockIdx.y * 32;
  const int lx = threadIdx.x & 31, ly = threadIdx.x >> 5;  // 32 x 8
#pragma unroll
  for (int j = 0; j < 4; ++j) {
    int r = r0 + ly + j * 8;
    if (r < R && c0 + lx < C) tile[ly + j * 8][lx] = src[(size_t)r * C + c0 + lx];
  }
  __syncthreads();
#pragma unroll
  for (int j = 0; j < 4; ++j) {
    int c = c0 + ly + j * 8;
    if (c < C && r0 + lx < R) dst[(size_t)c * ds + r0 + lx] = tile[lx][ly + j * 8];
  }
}

// ---------------- cross K/V precompute (once per call; plain stores, flushed at kernel end) ----------------
template<bool WT>
__global__ __launch_bounds__(256) void crosskv_k(
    const float* __restrict__ ctx, const float* __restrict__ Wm0,
    const float* __restrict__ bias0, float* __restrict__ ck, float* __restrict__ cv) {
  const int l = blockIdx.z;
  const float* Wm = Wm0 + (size_t)l * 2304 * 768;
  const float* bias = bias0 + l * 2304;
  __shared__ float a_s[16 * 768];
  __shared__ float ps[4 * 64 * 17];
  const int tid = threadIdx.x;
  const int row0 = blockIdx.y * 16;
  for (int i = tid * 4; i < 16 * 768; i += 1024) {
    int rr = i / 768, k = i - rr * 768;
    *(float4*)&a_s[i] = *(const float4*)&ctx[(size_t)(row0 + rr) * 768 + k];
  }
  __syncthreads();
  const int w = tid >> 6, lane = tid & 63;
  const int colg = 768 + blockIdx.x * 64 + lane;
  const int kb = w * 192;
  float acc[16];
#pragma unroll
  for (int r = 0; r < 16; ++r) acc[r] = 0.f;
  for (int k4 = 0; k4 < 48; ++k4) {
    const int k = kb + k4 * 4;
    float w0, w1, w2, w3;
    if (WT) {
      w0 = Wm[(size_t)(k + 0) * 2304 + colg]; w1 = Wm[(size_t)(k + 1) * 2304 + colg];
      w2 = Wm[(size_t)(k + 2) * 2304 + colg]; w3 = Wm[(size_t)(k + 3) * 2304 + colg];
    } else {
      float4 wv = *(const float4*)&Wm[(size_t)colg * 768 + k];
      w0 = wv.x; w1 = wv.y; w2 = wv.z; w3 = wv.w;
    }
#pragma unroll
    for (int r = 0; r < 16; ++r) {
      float4 a = *(const float4*)&a_s[r * 768 + k];
      acc[r] = fmaf(a.x, w0, fmaf(a.y, w1, fmaf(a.z, w2, fmaf(a.w, w3, acc[r]))));
    }
  }
#pragma unroll
  for (int r = 0; r < 16; ++r) ps[(w * 64 + lane) * 17 + r] = acc[r];
  __syncthreads();
  for (int o = tid; o < 1024; o += 256) {
    int rr = o >> 6, cl = o & 63;
    int cg = 768 + blockIdx.x * 64 + cl;
    float v = bias[cg];
#pragma unroll
    for (int ww = 0; ww < 4; ++ww) v += ps[(ww * 64 + cl) * 17 + rr];
    int gr = row0 + rr;
    int b = gr >> 7, s = gr & 127;
    int c = cg - 768, kv = c / 768, n = c - kv * 768;
    float* dst = kv ? cv : ck;
    dst[((size_t)(l * 4 + b) * 128 + s) * 768 + n] = v;
  }
}

// ================= persistent-decode stage functions =================
// Convention: weights / emb / pos / embT / ck / cv / smask are read-only -> plain cached loads.
// All RW activation buffers -> ldc/stc (agent-scope, L2-bypassing, lane-stride-1 coalesced).

// fused skinny GEMM (M=20, K=768), 64 cols/block, 4-wave in-block K-split.
// pre: 0 = stage xsrc raw; 1 = embed+pos (then LN); 2 = xsrc + tmp_in (then LN);
//      3 = xsrc + bias2 + sum of 4 ff2 partials (then LN)
// outmode: 0 plain, 1 relu, 2 tanh, 3 qkv-route (qb / kcl / vcl @ pos t)
template<bool WT>
__device__ void gemm_stage(int vb, float* UN,
    const float* __restrict__ Wm, int wstride, const float* __restrict__ bias, int N,
    int pre, const float* __restrict__ xsrc, const float* __restrict__ tmp_in,
    const float* __restrict__ lng, const float* __restrict__ lnb,
    float* __restrict__ xout, int outmode, float* __restrict__ out0,
    float* __restrict__ kcl, float* __restrict__ vcl, int t,
    const float* __restrict__ embp, const float* __restrict__ posw,
    const int* __restrict__ bufn,
    const float* __restrict__ pf, const float* __restrict__ bias2) {
  __shared__ float mS[RR], rS[RR];
  __shared__ int tokS[RR];
  const int tid = threadIdx.x;
  float* a_s = UN;
  if (pre == 1 && tid < RR) tokS[tid] = ldci(&bufn[tid * BUFL + t]);
  __syncthreads();
  // ---- stage A (20x768) into LDS; lane-stride-1 -> coalesced sc loads ----
  for (int i = tid; i < RR * 768; i += 256) {
    const int r = i / 768, k = i - r * 768;
    float v;
    if (pre == 0) {
      v = ldc(&xsrc[i]);
    } else if (pre == 1) {
      v = embp[(size_t)tokS[r] * 768 + k] + posw[(size_t)t * 768 + k];
    } else if (pre == 2) {
      v = ldc(&xsrc[i]) + ldc(&tmp_in[i]);
    } else {  // pre == 3: residual + ff2 bias + 4 split-K partials
      v = ldc(&xsrc[i]) + bias2[k] + ldc(&pf[i]) + ldc(&pf[15360 + i]) +
          ldc(&pf[30720 + i]) + ldc(&pf[46080 + i]);
    }
    a_s[i] = v;
  }
  __syncthreads();
  if (pre != 0) {
    // in-block LayerNorm (redundant across blocks; deterministic)
    const int wq = tid >> 6, ln = tid & 63;
    for (int r = wq * 5; r < wq * 5 + 5; ++r) {
      float s = 0.f, q = 0.f;
      for (int k = ln; k < 768; k += 64) { const float v = a_s[r * 768 + k]; s += v; q += v * v; }
      s = wave_sum(s); q = wave_sum(q);
      if (ln == 0) {
        const float m = s / 768.f;
        const float var = q / 768.f - m * m;
        mS[r] = m; rS[r] = 1.f / sqrtf(var + 1e-5f);
      }
    }
    __syncthreads();
    for (int i = tid * 4; i < RR * 768; i += 1024) {
      const int r = i / 768, k = i - r * 768;
      float4 v = *(const float4*)&a_s[i];
      const float4 g = *(const float4*)&lng[k];
      const float4 b = *(const float4*)&lnb[k];
      const float m = mS[r], rs = rS[r];
      v = make_float4((v.x - m) * rs * g.x + b.x, (v.y - m) * rs * g.y + b.y,
                      (v.z - m) * rs * g.z + b.z, (v.w - m) * rs * g.w + b.w);
      *(float4*)&a_s[i] = v;
    }
    __syncthreads();
    if (xout != nullptr && vb == 0) {
      for (int i = tid; i < RR * 768; i += 256) stc(&xout[i], a_s[i]);
    }
  }
  // ---- compute: wave w owns K-chunk [w*192, w*192+192), lane owns column ----
  const int w = tid >> 6, lane = tid & 63;
  const int colg = vb * 64 + lane;
  const int kb = w * 192;
  float acc[RR];
#pragma unroll
  for (int r = 0; r < RR; ++r) acc[r] = 0.f;
  for (int k4 = 0; k4 < 48; ++k4) {
    const int k = kb + k4 * 4;
    float w0, w1, w2, w3;
    if (WT) {
      w0 = Wm[(size_t)(k + 0) * wstride + colg];
      w1 = Wm[(size_t)(k + 1) * wstride + colg];
      w2 = Wm[(size_t)(k + 2) * wstride + colg];
      w3 = Wm[(size_t)(k + 3) * wstride + colg];
    } else {
      const float4 wv = *(const float4*)&Wm[(size_t)colg * 768 + k];
      w0 = wv.x; w1 = wv.y; w2 = wv.z; w3 = wv.w;
    }
#pragma unroll
    for (int r = 0; r < RR; ++r) {
      const float4 a = *(const float4*)&a_s[r * 768 + k];
      acc[r] = fmaf(a.x, w0, fmaf(a.y, w1, fmaf(a.z, w2, fmaf(a.w, w3, acc[r]))));
    }
  }
  __syncthreads();              // all waves done reading a_s -> ps may alias it
  float* ps = UN;
#pragma unroll
  for (int r = 0; r < RR; ++r) ps[(w * 64 + lane) * 21 + r] = acc[r];
  __syncthreads();
  for (int o = tid; o < RR * 64; o += 256) {
    const int r = o >> 6, cl = o & 63;
    const int cg = vb * 64 + cl;
    float v = bias[cg];
#pragma unroll
    for (int ww = 0; ww < 4; ++ww) v += ps[(ww * 64 + cl) * 21 + r];
    if (outmode == 1) v = fmaxf(v, 0.f);
    else if (outmode == 2) v = tanhf(v);
    if (outmode == 3) {
      if (cg < 768) stc(&out0[r * 768 + cg], v);
      else if (cg < 1536) stc(&kcl[(r * BUFL + t) * 768 + (cg - 768)], v);
      else stc(&vcl[(r * BUFL + t) * 768 + (cg - 1536)], v);
    } else {
      stc(&out0[(size_t)r * N + cg], v);
    }
  }
}

// KV-cache beam reorder (positions 0..t-1, old -> new by prevK); scalar, coalesced
__device__ void reorder_stage(int vb, int nb, int t,
    const float* __restrict__ kco, const float* __restrict__ vco,
    float* __restrict__ kcn, float* __restrict__ vcn, const int* __restrict__ prevK) {
  __shared__ int pkS[RR];
  if (threadIdx.x < RR) pkS[threadIdx.x] = ldci(&prevK[threadIdx.x]);
  __syncthreads();
  const int per = 768 * t;            // dwords per (row, half)
  const int tot = 2 * RR * per;
  for (int i = vb * 256 + (int)threadIdx.x; i < tot; i += nb * 256) {
    const int half = i / (RR * per);
    int rem = i - half * RR * per;
    const int r = rem / per;
    rem -= r * per;
    const int p2 = rem / 768;
    const int d = rem - p2 * 768;
    const int src = (r / BEAM) * BEAM + pkS[r];
    if (half == 0)
      stc(&kcn[(r * BUFL + p2) * 768 + d], ldc(&kco[(src * BUFL + p2) * 768 + d]));
    else
      stc(&vcn[(r * BUFL + p2) * 768 + d], ldc(&vco[(src * BUFL + p2) * 768 + d]));
  }
}

// self-attention: one (r,h) pair per block; 4-wave K staging, wave0 compute
__device__ void self_attn_stage(int vb, float* UN, const float* __restrict__ qb,
    const float* __restrict__ kcn, const float* __restrict__ vcn,
    float* __restrict__ outb, int t) {
  __shared__ float qs[64];
  __shared__ float pp[16];
  const int tid = threadIdx.x, w = tid >> 6, lane = tid & 63;
  const int r = vb % RR, hh = vb / RR;
  float* ks = UN;
  if (w == 0) qs[lane] = ldc(&qb[r * 768 + hh * 64 + lane]);
  for (int p2 = w; p2 <= t; p2 += 4)
    ks[p2 * 65 + lane] = ldc(&kcn[(r * BUFL + p2) * 768 + hh * 64 + lane]);
  __syncthreads();
  if (w == 0) {
    float s = -1e30f;
    if (lane <= t) {
      float a = 0.f;
#pragma unroll
      for (int d = 0; d < 64; ++d) a = fmaf(qs[d], ks[lane * 65 + d], a);
      s = a * 0.125f;
    }
    const float m = wave_max(s);
    const float pex = expf(s - m);        // lanes > t underflow to exact 0
    const float sum = wave_sum(pex);
    if (lane <= t) pp[lane] = pex / sum;
  }
  __syncthreads();
  if (w == 0) {
    const float* vbp = vcn + r * BUFL * 768 + hh * 64 + lane;
    float o = 0.f;
    for (int k = 0; k <= t; ++k) o = fmaf(pp[k], ldc(vbp + k * 768), o);
    stc(&outb[r * 768 + hh * 64 + lane], o);
  }
}

// cross-attention: one (r,h) pair per block; 4-wave K staging + 4-wave V split
// ck / cv are read-only (precomputed pre-kernel) -> plain cached loads.
__device__ void cross_attn_stage(int vb, float* UN, const float* __restrict__ qb,
    const float* __restrict__ ck, const float* __restrict__ cv,
    const int* __restrict__ smask, float* __restrict__ outb) {
  __shared__ float qs[64];
  __shared__ float pp[128];
  __shared__ float vpart[4 * 64];
  const int tid = threadIdx.x, w = tid >> 6, lane = tid & 63;
  const int r = vb % RR, hh = vb / RR, b = r / BEAM;
  float* ks = UN;
  if (w == 0) qs[lane] = ldc(&qb[r * 768 + hh * 64 + lane]);
  for (int p2 = w; p2 < 128; p2 += 4)
    ks[p2 * 65 + lane] = ck[((size_t)b * 128 + p2) * 768 + hh * 64 + lane];
  __syncthreads();
  if (w == 0) {
    float a0 = 0.f, a1 = 0.f;
#pragma unroll
    for (int d = 0; d < 64; ++d) {
      a0 = fmaf(qs[d], ks[lane * 65 + d], a0);
      a1 = fmaf(qs[d], ks[(lane + 64) * 65 + d], a1);
    }
    float s0 = a0 * 0.125f, s1 = a1 * 0.125f;
    if (smask[b * 128 + lane] == 0)      s0 = -1e9f;
    if (smask[b * 128 + lane + 64] == 0) s1 = -1e9f;
    const float m = wave_max(fmaxf(s0, s1));
    const float p0 = expf(s0 - m), p1 = expf(s1 - m);
    const float sum = wave_sum(p0 + p1);
    pp[lane] = p0 / sum; pp[lane + 64] = p1 / sum;
  }
  __syncthreads();
  {
    const float* vbp = cv + (size_t)b * 128 * 768 + hh * 64 + lane;
    float o0 = 0.f, o1 = 0.f, o2 = 0.f, o3 = 0.f;
    for (int k = w * 32; k < w * 32 + 32; k += 4) {
      o0 = fmaf(pp[k + 0], vbp[(k + 0) * 768], o0);
      o1 = fmaf(pp[k + 1], vbp[(k + 1) * 768], o1);
      o2 = fmaf(pp[k + 2], vbp[(k + 2) * 768], o2);
      o3 = fmaf(pp[k + 3], vbp[(k + 3) * 768], o3);
    }
    vpart[w * 64 + lane] = (o0 + o1) + (o2 + o3);
  }
  __syncthreads();
  if (w == 0)
    stc(&outb[r * 768 + hh * 64 + lane],
        (vpart[lane] + vpart[64 + lane]) + (vpart[128 + lane] + vpart[192 + lane]));
}

// ff2 split-K partials: 192 blocks = 4 k-tiles(768) x 48 col-tiles(16).
// A k-slice staged into LDS first (coalesced sc loads once), compute reads LDS.
template<bool WT>
__device__ void ff2A_stage(int vb, float* UN, const float* __restrict__ Wm,
                           const float* __restrict__ A, float* __restrict__ pf) {
  const int tid = threadIdx.x, w = tid >> 6, lane = tid & 63;
  const int cl = lane & 15, ksub = lane >> 4;
  const int kt = vb / 48, ct = vb - kt * 48;
  // stage A[:, kt*768 .. kt*768+768) into UN (20x768), lane-stride-1 coalesced
  for (int i = tid; i < RR * 768; i += 256) {
    const int r = i / 768, kk = i - r * 768;
    UN[i] = ldc(&A[r * 3072 + kt * 768 + kk]);
  }
  __syncthreads();
  const int colg = ct * 16 + cl;
  const int kb = w * 192 + ksub * 48;          // local k within the 768 slice
  float acc[RR];
#pragma unroll
  for (int r = 0; r < RR; ++r) acc[r] = 0.f;
  for (int k4 = 0; k4 < 12; ++k4) {
    const int k = kb + k4 * 4;
    const int kg = kt * 768 + k;               // global k for weight indexing
    float w0, w1, w2, w3;
    if (WT) {
      w0 = Wm[(size_t)(kg + 0) * 768 + colg];
      w1 = Wm[(size_t)(kg + 1) * 768 + colg];
      w2 = Wm[(size_t)(kg + 2) * 768 + colg];
      w3 = Wm[(size_t)(kg + 3) * 768 + colg];
    } else {
      const float4 wv = *(const float4*)&Wm[(size_t)colg * 3072 + kg];
      w0 = wv.x; w1 = wv.y; w2 = wv.z; w3 = wv.w;
    }
#pragma unroll
    for (int r = 0; r < RR; ++r) {
      const float4 a = *(const float4*)&UN[r * 768 + k];
      acc[r] = fmaf(a.x, w0, fmaf(a.y, w1, fmaf(a.z, w2, fmaf(a.w, w3, acc[r]))));
    }
  }
  __syncthreads();             // done reading staged A -> ps may alias UN
  float* ps = UN;
  const int seg = w * 4 + ksub;                // 0..15
#pragma unroll
  for (int r = 0; r < RR; ++r) ps[(seg * 16 + cl) * 21 + r] = acc[r];
  __syncthreads();
  for (int o = tid; o < RR * 16; o += 256) {
    const int r = o >> 4, c2 = o & 15;
    float v = 0.f;
#pragma unroll
    for (int s2 = 0; s2 < 16; ++s2) v += ps[(s2 * 16 + c2) * 21 + r];
    stc(&pf[kt * 15360 + r * 768 + ct * 16 + c2], v);
  }
}

// logits + per-block online-softmax partials + per-(block,row) top-5
template<bool ET>
__device__ void logits_stage(int blk, float* UN,
    const float* __restrict__ hbuf, const float* __restrict__ embM,
    float* __restrict__ candV, int* __restrict__ candI,
    float* __restrict__ mrow, float* __restrict__ srow) {
  __shared__ float vv[4 * 256];
  float* hs = UN;
  const int tid = threadIdx.x;
  for (int i = tid; i < RR * 768; i += 256) hs[i] = ldc(&hbuf[i]);
  __syncthreads();
  const int col = blk * 256 + tid;
  const bool valid = col < kV;
  const int colc = valid ? col : (kV - 1);
  float acc[RR];
#pragma unroll
  for (int r = 0; r < RR; ++r) acc[r] = 0.f;
  for (int k = 0; k < 768; k += 4) {
    float w0, w1, w2, w3;
    if (ET) {
      w0 = embM[(size_t)(k + 0) * kVP + col];
      w1 = embM[(size_t)(k + 1) * kVP + col];
      w2 = embM[(size_t)(k + 2) * kVP + col];
      w3 = embM[(size_t)(k + 3) * kVP + col];
    } else {
      const float4 wv = *(const float4*)&embM[(size_t)colc * 768 + k];
      w0 = wv.x; w1 = wv.y; w2 = wv.z; w3 = wv.w;
    }
#pragma unroll
    for (int r = 0; r < RR; ++r) {
      const float4 a = *(const float4*)&hs[r * 768 + k];
      acc[r] = fmaf(a.x, w0, fmaf(a.y, w1, fmaf(a.z, w2, fmaf(a.w, w3, acc[r]))));
    }
  }
  const int w = tid >> 6, lane = tid & 63;
  for (int g = 0; g < 5; ++g) {      // rows 4g..4g+3; wave w handles row 4g+w
#pragma unroll
    for (int j = 0; j < 4; ++j) vv[j * 256 + tid] = valid ? acc[g * 4 + j] : -FLT_MAX;
    __syncthreads();
    const int r = g * 4 + w;
    float v[4]; int gc[4]; bool used[4];
#pragma unroll
    for (int j = 0; j < 4; ++j) {
      v[j] = vv[w * 256 + lane * 4 + j];
      gc[j] = blk * 256 + lane * 4 + j;
      used[j] = false;
    }
    float tv[5]; int tg[5];
#pragma unroll
    for (int round = 0; round < 5; ++round) {
      float bv = -FLT_MAX; int bidx = 0x7fffffff; int bj = -1;
#pragma unroll
      for (int j = 0; j < 4; ++j) {
        const bool c = (!used[j]) && better(v[j], gc[j], bv, bidx);
        bv = c ? v[j] : bv; bidx = c ? gc[j] : bidx; bj = c ? j : bj;
      }
      float wv2 = bv; int wi = bidx;
      for (int d = 1; d < 64; d <<= 1) {
        const float ov = __shfl_xor(wv2, d, 64); const int oi = __shfl_xor(wi, d, 64);
        if (better(ov, oi, wv2, wi)) { wv2 = ov; wi = oi; }
      }
      tv[round] = wv2; tg[round] = wi;
      if (bj >= 0 && bidx == wi) used[bj] = true;
    }
    const float m = tv[0];
    float s = 0.f;
#pragma unroll
    for (int j = 0; j < 4; ++j) s += expf(v[j] - m);   // -FLT_MAX -> 0
    s = wave_sum(s);
    if (lane == 0) {
      stc(&mrow[r * LB + blk], m);
      stc(&srow[r * LB + blk], s);
#pragma unroll
      for (int q = 0; q < 5; ++q) {
        stc(&candV[(r * LB + blk) * 5 + q], tv[q]);
        stci(&candI[(r * LB + blk) * 5 + q], tg[q]);
      }
    }
    __syncthreads();
  }
}

// per-batch top-5 over candidates + lse-reduce + buf reorder
__device__ void topk_stage(int b, const float* __restrict__ candV, const int* __restrict__ candI,
    const float* __restrict__ mrow, const float* __restrict__ srow,
    float* __restrict__ scores, const int* __restrict__ bufc, int* __restrict__ bufn,
    int t, int* __restrict__ prevK, int* __restrict__ tokv) {
  const int tid = threadIdx.x;
  const int w = tid >> 6, lane = tid & 63;
  __shared__ float lseS[5], scS[5];
  __shared__ int emS[5];
  __shared__ float wv5[4][5]; __shared__ int wi5[4][5];
  __shared__ int fpk[5], ftok[5];
  for (int j = w; j < 5; j += 4) {
    const int gr = b * 5 + j;
    float M = -FLT_MAX, S = 0.f;
    for (int e = lane; e < LB; e += 64) {
      const float m2 = ldc(&mrow[gr * LB + e]), s2 = ldc(&srow[gr * LB + e]);
      if (m2 > M) { S = S * expf(M - m2) + s2; M = m2; }
      else        { S += s2 * expf(m2 - M); }
    }
    for (int d = 1; d < 64; d <<= 1) {
      const float Mo = __shfl_xor(M, d, 64), So = __shfl_xor(S, d, 64);
      const float Mn = fmaxf(M, Mo);
      S = S * expf(M - Mn) + So * expf(Mo - Mn);
      M = Mn;
    }
    if (lane == 0) {
      lseS[j] = M + logf(S);
      scS[j] = ldc(&scores[gr]);
      emS[j] = (ldci(&bufc[gr * BUFL + t]) == EOSt);
    }
  }
  __syncthreads();
  float tv[5]; int ti[5];
#pragma unroll
  for (int s = 0; s < 5; ++s) { tv[s] = -FLT_MAX; ti[s] = 0x7fffffff; }
  for (int i = tid; i < 5 * LB * 5; i += 256) {
    const int j = i / (LB * 5);
    const int e = i - j * (LB * 5);
    const int blk = e / 5, rk = e - blk * 5;
    const int gr = b * 5 + j;
    const float cvv = ldc(&candV[(gr * LB + blk) * 5 + rk]);
    const int col = ldci(&candI[(gr * LB + blk) * 5 + rk]);
    const float val = emS[j] ? NEGV : (cvv - lseS[j] + scS[j]);
    insert5(tv, ti, val, j * kV + col);
  }
  for (int d = 1; d < 64; d <<= 1) {
    float ov[5]; int oi[5];
#pragma unroll
    for (int s = 0; s < 5; ++s) { ov[s] = __shfl_xor(tv[s], d, 64); oi[s] = __shfl_xor(ti[s], d, 64); }
    merge5(tv, ti, ov, oi);
  }
  if (lane == 0) {
#pragma unroll
    for (int s = 0; s < 5; ++s) { wv5[w][s] = tv[s]; wi5[w][s] = ti[s]; }
  }
  __syncthreads();
  if (tid == 0) {
    float av[5]; int ai[5];
#pragma unroll
    for (int s = 0; s < 5; ++s) { av[s] = wv5[0][s]; ai[s] = wi5[0][s]; }
    for (int ww = 1; ww < 4; ++ww) {
      float bv[5]; int bi[5];
#pragma unroll
      for (int s = 0; s < 5; ++s) { bv[s] = wv5[ww][s]; bi[s] = wi5[ww][s]; }
      merge5(av, ai, bv, bi);
    }
#pragma unroll
    for (int s = 0; s < 5; ++s) {
      const int pk = ai[s] / kV;
      const int tk = ai[s] - pk * kV;
      stc(&scores[b * 5 + s], av[s]);
      stci(&prevK[b * 5 + s], pk); stci(&tokv[b * 5 + s], tk);
      fpk[s] = pk; ftok[s] = tk;
    }
  }
  __syncthreads();
  for (int i = tid; i < 5 * BUFL; i += 256) {
    const int j = i / BUFL, p2 = i - j * BUFL;
    const int src = b * 5 + fpk[j];
    const int val = (p2 == t + 1) ? ftok[j] : ldci(&bufc[src * BUFL + p2]);
    stci(&bufn[(b * 5 + j) * BUFL + p2], val);
  }
}

// ================= the persistent decode kernel =================
struct DecP {
  const float *emb, *pos, *ln_emb_g, *ln_emb_b;
  const float *self_in_b, *self_out_b, *cross_in_b, *cross_out_b;
  const float *ff1_b, *ff2_b, *dense_b;
  const float *ln1_g, *ln1_b, *ln2_g, *ln2_b, *ln3_g, *ln3_b;
  const int* smask;
  const float *Wqkv0, *Wqkv1, *Wso0, *Wso1, *Wcq0, *Wcq1, *Wco0, *Wco1;
  const float *Wf10, *Wf11, *Wf20, *Wf21, *Wd, *embM;
  float *XA, *XB, *XC, *qb, *attnb, *tmp, *hbuf, *ffb, *pf;
  float *candV, *mrow, *srow, *scores;
  float *ck, *cv, *kcB, *vcB;
  int *candI, *bufs0, *bufs1, *prevK, *tok;
  int* bar;
  float* out;
};

template<bool WT, bool ET>
__global__ __launch_bounds__(256) void decode_k(DecP p) {
  __shared__ float UN[15360];   // A-tile / K-stage / partial-sum union (61.4 KB)
  const int vb = blockIdx.x;
  int bs = 0;
#pragma unroll 1
  for (int t = 0; t < TMAX; ++t) {
    const int* bc = (t & 1) ? p.bufs1 : p.bufs0;
    int* bn = (t & 1) ? p.bufs0 : p.bufs1;
    const int np = (t + 1) & 1, op = t & 1;
#pragma unroll 1
    for (int l = 0; l < 2; ++l) {
      float* kNew = p.kcB + (size_t)(np * 2 + l) * CSEG;
      float* vNew = p.vcB + (size_t)(np * 2 + l) * CSEG;
      const float* kOld = p.kcB + (size_t)(op * 2 + l) * CSEG;
      const float* vOld = p.vcB + (size_t)(op * 2 + l) * CSEG;
      // ---- qkv (36 blocks) + cache reorder (remaining blocks) ----
      if (vb < 36) {
        if (l == 0)
          gemm_stage<WT>(vb, UN, p.Wqkv0, 2304, p.self_in_b, 2304,
                         1, nullptr, nullptr, p.ln_emb_g, p.ln_emb_b, p.XA,
                         3, p.qb, kNew, vNew, t, p.emb, p.pos, bc, nullptr, nullptr);
        else
          gemm_stage<WT>(vb, UN, p.Wqkv1, 2304, p.self_in_b + 2304, 2304,
                         3, p.XC, nullptr, p.ln3_g, p.ln3_b, p.XA,
                         3, p.qb, kNew, vNew, t, nullptr, nullptr, nullptr,
                         p.pf, p.ff2_b);
      } else if (t > 0) {
        reorder_stage(vb - 36, NBLK - 36, t, kOld, vOld, kNew, vNew, p.prevK);
      }
      grid_sync(p.bar, ++bs);
      // ---- self attention (240 blocks, one (r,h) each) ----
      if (vb < RR * 12) self_attn_stage(vb, UN, p.qb, kNew, vNew, p.attnb, t);
      grid_sync(p.bar, ++bs);
      // ---- self out-proj -> tmp ----
      if (vb < 12)
        gemm_stage<WT>(vb, UN, l ? p.Wso1 : p.Wso0, 768, p.self_out_b + l * 768, 768,
                       0, p.attnb, nullptr, nullptr, nullptr, nullptr,
                       0, p.tmp, nullptr, nullptr, t,
                       nullptr, nullptr, nullptr, nullptr, nullptr);
      grid_sync(p.bar, ++bs);
      // ---- cross q (+ln1), writes XB ----
      if (vb < 12)
        gemm_stage<WT>(vb, UN, l ? p.Wcq1 : p.Wcq0, 2304, p.cross_in_b + l * 2304, 768,
                       2, p.XA, p.tmp, p.ln1_g + l * 768, p.ln1_b + l * 768, p.XB,
                       0, p.qb, nullptr, nullptr, t,
                       nullptr, nullptr, nullptr, nullptr, nullptr);
      grid_sync(p.bar, ++bs);
      // ---- cross attention ----
      if (vb < RR * 12)
        cross_attn_stage(vb, UN, p.qb,
                         p.ck + (size_t)l * 4 * 128 * 768,
                         p.cv + (size_t)l * 4 * 128 * 768, p.smask, p.attnb);
      grid_sync(p.bar, ++bs);
      // ---- cross out-proj -> tmp ----
      if (vb < 12)
        gemm_stage<WT>(vb, UN, l ? p.Wco1 : p.Wco0, 768, p.cross_out_b + l * 768, 768,
                       0, p.attnb, nullptr, nullptr, nullptr, nullptr,
                       0, p.tmp, nullptr, nullptr, t,
                       nullptr, nullptr, nullptr, nullptr, nullptr);
      grid_sync(p.bar, ++bs);
      // ---- ff1 (+ln2), writes XC ----
      if (vb < 48)
        gemm_stage<WT>(vb, UN, l ? p.Wf11 : p.Wf10, 3072, p.ff1_b + l * 3072, 3072,
                       2, p.XB, p.tmp, p.ln2_g + l * 768, p.ln2_b + l * 768, p.XC,
                       1, p.ffb, nullptr, nullptr, t,
                       nullptr, nullptr, nullptr, nullptr, nullptr);
      grid_sync(p.bar, ++bs);
      // ---- ff2 split-K partials (bias + reduce folded into consumer pre==3) ----
      if (vb < 192) ff2A_stage<WT>(vb, UN, l ? p.Wf21 : p.Wf20, p.ffb, p.pf);
      grid_sync(p.bar, ++bs);
    }
    // ---- dense head (+ln3 layer1, tanh) -> hbuf ----
    if (vb < 12)
      gemm_stage<WT>(vb, UN, p.Wd, 768, p.dense_b, 768,
                     3, p.XC, nullptr, p.ln3_g + 768, p.ln3_b + 768, nullptr,
                     2, p.hbuf, nullptr, nullptr, t,
                     nullptr, nullptr, nullptr, p.pf, p.ff2_b + 768);
    grid_sync(p.bar, ++bs);
    // ---- logits partials ----
    if (vb < LB) logits_stage<ET>(vb, UN, p.hbuf, p.embM, p.candV, p.candI, p.mrow, p.srow);
    grid_sync(p.bar, ++bs);
    // ---- top-k + buf reorder ----
    if (vb < BB) topk_stage(vb, p.candV, p.candI, p.mrow, p.srow, p.scores, bc, bn, t, p.prevK, p.tok);
    grid_sync(p.bar, ++bs);
  }
  // ---- finalize (buf parity: t=15 wrote bufs0) ----
  if (vb == 0) {
    const int tid = threadIdx.x;
    if (tid < RR) {
      p.out[tid] = ldc(&p.scores[tid]);
      int seen = 0;
      for (int i = 0; i < TMAX; ++i) {
        const int tk = ldci(&p.bufs0[tid * BUFL + 1 + i]);
        if (tk == EOSt) seen = 1;
        p.out[RR + tid * TMAX + i] = seen ? 0.f : (float)tk;
      }
    }
  }
}

// ================= host side =================
extern "C" void kernel_launch(void* const* d_in, const int* in_sizes, int n_in,
                              void* d_out, int out_size, void* d_ws, size_t ws_size,
                              hipStream_t stream) {
  const float* emb        = (const float*)d_in[0];
  const float* pos        = (const float*)d_in[1];
  const float* ln_emb_g   = (const float*)d_in[2];
  const float* ln_emb_b   = (const float*)d_in[3];
  const float* self_in_w  = (const float*)d_in[4];
  const float* self_in_b  = (const float*)d_in[5];
  const float* self_out_w = (const float*)d_in[6];
  const float* self_out_b = (const float*)d_in[7];
  const float* cross_in_w = (const float*)d_in[8];
  const float* cross_in_b = (const float*)d_in[9];
  const float* cross_out_w= (const float*)d_in[10];
  const float* cross_out_b= (const float*)d_in[11];
  const float* ff1_w      = (const float*)d_in[12];
  const float* ff1_b      = (const float*)d_in[13];
  const float* ff2_w      = (const float*)d_in[14];
  const float* ff2_b      = (const float*)d_in[15];
  const float* ln1_g      = (const float*)d_in[16];
  const float* ln1_b      = (const float*)d_in[17];
  const float* ln2_g      = (const float*)d_in[18];
  const float* ln2_b      = (const float*)d_in[19];
  const float* ln3_g      = (const float*)d_in[20];
  const float* ln3_b      = (const float*)d_in[21];
  const float* dense_w    = (const float*)d_in[22];
  const float* dense_b    = (const float*)d_in[23];
  const float* context    = (const float*)d_in[24];
  const int*   source_mask= (const int*)d_in[25];

  float* wsf = (float*)d_ws;
  size_t off = 0;
  auto alloc = [&](size_t n) { float* p = wsf + off; off += (n + 3) & ~(size_t)3; return p; };

  float* XA    = alloc(RR * 768);
  float* XB    = alloc(RR * 768);
  float* XC    = alloc(RR * 768);
  float* qb    = alloc(RR * 768);
  float* attnb = alloc(RR * 768);
  float* tmp   = alloc(RR * 768);
  float* hbuf  = alloc(RR * 768);
  float* ffb   = alloc(RR * 3072);
  float* candV = alloc(RR * LB * 5);
  float* mrow  = alloc(RR * LB);
  float* srow  = alloc(RR * LB);
  float* scores= alloc(32);
  float* ck    = alloc((size_t)NLY * 4 * 128 * 768);
  float* cv    = alloc((size_t)NLY * 4 * 128 * 768);
  float* kcB   = alloc(4 * CSEG);                 // [pp][l]
  float* vcB   = alloc(4 * CSEG);
  float* pf    = alloc(4 * RR * 768);             // ff2 split-K partials
  int* candI   = (int*)alloc(RR * LB * 5);
  int* bufs0   = (int*)alloc(RR * BUFL + 12);
  int* bufs1   = (int*)alloc(RR * BUFL + 12);
  int* prevKp  = (int*)alloc(32);
  int* tokp    = (int*)alloc(32);
  int* bar     = (int*)alloc(1024);               // padded barrier lines
  const size_t baseFloats = off;

  // transposed weights
  const size_t nSiT = (size_t)768 * 2304, nSoT = (size_t)768 * 768;
  const size_t nCiT = nSiT, nCoT = nSoT, nF1T = (size_t)768 * 3072, nF2T = (size_t)3072 * 768;
  const size_t wtFloats = 2 * (nSiT + nSoT + nCiT + nCoT + nF1T + nF2T) + nSoT;
  const size_t embTFloats = (size_t)768 * kVP;
  const bool useWT = ws_size >= (baseFloats + wtFloats) * 4;
  const bool useET = useWT && ws_size >= (baseFloats + wtFloats + embTFloats) * 4;

  float* siT[2]; float* soT[2]; float* ciT[2]; float* coT[2]; float* f1T[2]; float* f2T[2];
  float* dT = nullptr; float* embT = nullptr;
  if (useWT) {
    for (int l = 0; l < 2; ++l) siT[l] = alloc(nSiT);
    for (int l = 0; l < 2; ++l) soT[l] = alloc(nSoT);
    for (int l = 0; l < 2; ++l) ciT[l] = alloc(nCiT);
    for (int l = 0; l < 2; ++l) coT[l] = alloc(nCoT);
    for (int l = 0; l < 2; ++l) f1T[l] = alloc(nF1T);
    for (int l = 0; l < 2; ++l) f2T[l] = alloc(nF2T);
    dT = alloc(nSoT);
    if (useET) embT = alloc(embTFloats);
  }

  init_k<<<1, 512, 0, stream>>>(bufs0, scores, bar);

  if (useWT) {
    auto T = [&](const float* src, float* dst, int R, int C, int ds) {
      dim3 g((C + 31) / 32, (R + 31) / 32);
      transpose_k<<<g, 256, 0, stream>>>(src, dst, R, C, ds);
    };
    for (int l = 0; l < 2; ++l) {
      T(self_in_w  + (size_t)l * 2304 * 768, siT[l], 2304, 768, 2304);
      T(self_out_w + (size_t)l * 768 * 768,  soT[l], 768, 768, 768);
      T(cross_in_w + (size_t)l * 2304 * 768, ciT[l], 2304, 768, 2304);
      T(cross_out_w+ (size_t)l * 768 * 768,  coT[l], 768, 768, 768);
      T(ff1_w      + (size_t)l * 3072 * 768, f1T[l], 3072, 768, 3072);
      T(ff2_w      + (size_t)l * 768 * 3072, f2T[l], 768, 3072, 768);
    }
    T(dense_w, dT, 768, 768, 768);
    if (useET) T(emb, embT, kV, 768, kVP);
  }

  // cross K/V (once)
  {
    dim3 g(24, 32, 2);
    if (useWT) crosskv_k<true><<<g, 256, 0, stream>>>(context, ciT[0], cross_in_b, ck, cv);
    else       crosskv_k<false><<<g, 256, 0, stream>>>(context, cross_in_w, cross_in_b, ck, cv);
  }

  DecP P;
  P.emb = emb; P.pos = pos; P.ln_emb_g = ln_emb_g; P.ln_emb_b = ln_emb_b;
  P.self_in_b = self_in_b; P.self_out_b = self_out_b;
  P.cross_in_b = cross_in_b; P.cross_out_b = cross_out_b;
  P.ff1_b = ff1_b; P.ff2_b = ff2_b; P.dense_b = dense_b;
  P.ln1_g = ln1_g; P.ln1_b = ln1_b; P.ln2_g = ln2_g; P.ln2_b = ln2_b;
  P.ln3_g = ln3_g; P.ln3_b = ln3_b;
  P.smask = source_mask;
  if (useWT) {
    P.Wqkv0 = siT[0]; P.Wqkv1 = siT[1]; P.Wso0 = soT[0]; P.Wso1 = soT[1];
    P.Wcq0 = ciT[0]; P.Wcq1 = ciT[1]; P.Wco0 = coT[0]; P.Wco1 = coT[1];
    P.Wf10 = f1T[0]; P.Wf11 = f1T[1]; P.Wf20 = f2T[0]; P.Wf21 = f2T[1];
    P.Wd = dT; P.embM = useET ? embT : emb;
  } else {
    P.Wqkv0 = self_in_w; P.Wqkv1 = self_in_w + (size_t)2304 * 768;
    P.Wso0 = self_out_w; P.Wso1 = self_out_w + (size_t)768 * 768;
    P.Wcq0 = cross_in_w; P.Wcq1 = cross_in_w + (size_t)2304 * 768;
    P.Wco0 = cross_out_w; P.Wco1 = cross_out_w + (size_t)768 * 768;
    P.Wf10 = ff1_w; P.Wf11 = ff1_w + (size_t)3072 * 768;
    P.Wf20 = ff2_w; P.Wf21 = ff2_w + (size_t)768 * 3072;
    P.Wd = dense_w; P.embM = emb;
  }
  P.XA = XA; P.XB = XB; P.XC = XC; P.qb = qb; P.attnb = attnb; P.tmp = tmp;
  P.hbuf = hbuf; P.ffb = ffb; P.pf = pf;
  P.candV = candV; P.mrow = mrow; P.srow = srow; P.scores = scores;
  P.ck = ck; P.cv = cv; P.kcB = kcB; P.vcB = vcB;
  P.candI = candI; P.bufs0 = bufs0; P.bufs1 = bufs1; P.prevK = prevKp; P.tok = tokp;
  P.bar = bar; P.out = (float*)d_out;

  if (useET)      decode_k<true,  true ><<<NBLK, 256, 0, stream>>>(P);
  else if (useWT) decode_k<true,  false><<<NBLK, 256, 0, stream>>>(P);
  else            decode_k<false, false><<<NBLK, 256, 0, stream>>>(P);
}